// Round 5
// baseline (1039.794 us; speedup 1.0000x reference)
//
#include <hip/hip_runtime.h>
#include <hip/hip_fp16.h>
#include <math.h>

#define NN 50000
#define EE 800000
#define NHEAD 8
#define BN_EPS 1e-5f

typedef _Float16 half8_t __attribute__((ext_vector_type(8)));
typedef float float4_t __attribute__((ext_vector_type(4)));

// monotone float<->uint encoding for atomicMax on signed floats
__device__ __forceinline__ unsigned fenc(float f) {
  unsigned u = __float_as_uint(f);
  return (u & 0x80000000u) ? ~u : (u | 0x80000000u);
}
__device__ __forceinline__ float fdec(unsigned k) {
  return (k & 0x80000000u) ? __uint_as_float(k & 0x7fffffffu)
                           : __uint_as_float(~k);
}

// ---------------------------------------------------------------------------
// Unified MFMA GEMM: C[M,NC] = A[M,KDIM] @ B, Bt = B^T [NC][KDIM] fp16.
// AT=float: A loaded fp32, optionally BN(scale/shift)+relu applied (ABN).
// STATS: fused BatchNorm column sum/sumsq accumulation (atomicAdd).
// RESIDBN: adds relu(bn(residf[row,col])) to output (embed residual).
// CLR: block 0 zeroes 16 uints (elmax) for the following eler pass.
// ---------------------------------------------------------------------------
template <int KDIM, int NC, typename AT, bool ABN, bool RESIDBN, bool STATS,
          bool F16OUT, bool F32OUT, bool CLR>
__global__ __launch_bounds__(256)
void mfma_gemm_k(const AT* __restrict__ A, const _Float16* __restrict__ Bt,
                 const float* __restrict__ bn, float* __restrict__ statsOut,
                 const float* __restrict__ residf, _Float16* __restrict__ Ch,
                 float* __restrict__ Cf, unsigned* __restrict__ clrp, int M) {
  constexpr int NT = NC / 16;
  const int lane = threadIdx.x & 63, wave = threadIdx.x >> 6;
  const int q = lane >> 4, l16 = lane & 15;
  const int row0 = blockIdx.x * 128 + wave * 32;
  if constexpr (CLR) {
    if (blockIdx.x == 0 && threadIdx.x < 16) clrp[threadIdx.x] = 0u;
  }
  float4_t acc[2][NT];
#pragma unroll
  for (int i = 0; i < 2; ++i)
#pragma unroll
    for (int j = 0; j < NT; ++j) acc[i][j] = (float4_t){0.f, 0.f, 0.f, 0.f};

#pragma unroll
  for (int kk = 0; kk < KDIM / 32; ++kk) {
    float scv[8], shv[8];
    if constexpr (ABN) {
      int kb = kk * 32 + q * 8;
#pragma unroll
      for (int x = 0; x < 8; ++x) { scv[x] = bn[256 + kb + x]; shv[x] = bn[384 + kb + x]; }
    }
    half8_t a[2];
#pragma unroll
    for (int i = 0; i < 2; ++i) {
      int r = row0 + i * 16 + l16;
      r = (r < M) ? r : (M - 1);
      if constexpr (__is_same(AT, _Float16)) {
        a[i] = *(const half8_t*)(A + (size_t)r * KDIM + kk * 32 + q * 8);
      } else {
        const float* ap = (const float*)A + (size_t)r * KDIM + kk * 32 + q * 8;
        float4 v0 = *(const float4*)ap, v1 = *(const float4*)(ap + 4);
        float t[8] = {v0.x, v0.y, v0.z, v0.w, v1.x, v1.y, v1.z, v1.w};
        if constexpr (ABN) {
#pragma unroll
          for (int x = 0; x < 8; ++x) t[x] = fmaxf(t[x] * scv[x] + shv[x], 0.f);
        }
        half8_t hv;
#pragma unroll
        for (int x = 0; x < 8; ++x) hv[x] = (_Float16)t[x];
        a[i] = hv;
      }
    }
#pragma unroll
    for (int j = 0; j < NT; ++j) {
      half8_t b = *(const half8_t*)(Bt + (size_t)(j * 16 + l16) * KDIM + kk * 32 + q * 8);
      acc[0][j] = __builtin_amdgcn_mfma_f32_16x16x32_f16(a[0], b, acc[0][j], 0, 0, 0);
      acc[1][j] = __builtin_amdgcn_mfma_f32_16x16x32_f16(a[1], b, acc[1][j], 0, 0, 0);
    }
  }

  // store epilogue (C/D: col=lane&15, row=(lane>>4)*4+reg)
  float rsc[NT], rsh[NT];
  if constexpr (RESIDBN) {
#pragma unroll
    for (int j = 0; j < NT; ++j) { rsc[j] = bn[256 + j * 16 + l16]; rsh[j] = bn[384 + j * 16 + l16]; }
  }
#pragma unroll
  for (int i = 0; i < 2; ++i)
#pragma unroll
    for (int j = 0; j < NT; ++j)
#pragma unroll
      for (int r = 0; r < 4; ++r) {
        int row = row0 + i * 16 + q * 4 + r;
        if (row >= M) continue;
        int col = j * 16 + l16;
        float v = acc[i][j][r];
        if constexpr (RESIDBN) {
          float rv = residf[(size_t)row * NC + col];
          v += fmaxf(rv * rsc[j] + rsh[j], 0.f);
        }
        if constexpr (F32OUT) Cf[(size_t)row * NC + col] = v;
        if constexpr (F16OUT) Ch[(size_t)row * NC + col] = (_Float16)v;
      }

  if constexpr (STATS) {
    float sc_[NT], sq_[NT];
#pragma unroll
    for (int j = 0; j < NT; ++j) {
      float s = 0.f, qq = 0.f;
#pragma unroll
      for (int i = 0; i < 2; ++i)
#pragma unroll
        for (int r = 0; r < 4; ++r) {
          int row = row0 + i * 16 + q * 4 + r;
          float x = (row < M) ? acc[i][j][r] : 0.f;
          s += x; qq += x * x;
        }
      sc_[j] = s; sq_[j] = qq;
    }
#pragma unroll
    for (int j = 0; j < NT; ++j) {
      sc_[j] += __shfl_xor(sc_[j], 16, 64);
      sq_[j] += __shfl_xor(sq_[j], 16, 64);
      sc_[j] += __shfl_xor(sc_[j], 32, 64);
      sq_[j] += __shfl_xor(sq_[j], 32, 64);
    }
    if (lane < 16) {
#pragma unroll
      for (int j = 0; j < NT; ++j) {
        atomicAdd(&statsOut[j * 16 + l16], sc_[j]);
        atomicAdd(&statsOut[128 + j * 16 + l16], sq_[j]);
      }
    }
  }
}

// ---------------------------------------------------------------------------
// weight transpose + fp32->fp16 (12 matrices) + zero both BN stats buffers
// ---------------------------------------------------------------------------
struct TJob { const float* src; _Float16* dst; int k, n; };
struct TJobs { TJob j[12]; };

__global__ __launch_bounds__(256)
void transpose_k(TJobs jobs, float* __restrict__ statsz) {
  if (blockIdx.x == 0) {
    for (int i = threadIdx.x; i < 1024; i += 256) statsz[i] = 0.f;
  }
  TJob job = jobs.j[blockIdx.x];
  int total = job.k * job.n;
  for (int i = threadIdx.x; i < total; i += 256) {
    int kk = i / job.n, nn = i % job.n;
    job.dst[(size_t)nn * job.k + kk] = (_Float16)job.src[i];
  }
}

__global__ void bn_final_k(float* stats, const float* __restrict__ gamma,
                           const float* __restrict__ beta) {
  int c = threadIdx.x;  // 128 threads
  float mean = stats[c] * (1.f / NN);
  float var = stats[128 + c] * (1.f / NN) - mean * mean;
  var = fmaxf(var, 0.f);
  float sc = gamma[c] * rsqrtf(var + BN_EPS);
  stats[256 + c] = sc;
  stats[384 + c] = beta[c] - mean * sc;
}

// ---------------------------------------------------------------------------
// attention logits for BOTH relations + per-head global el max (encoded)
// ---------------------------------------------------------------------------
__global__ __launch_bounds__(256)
void eler_k(const __half2* __restrict__ f0, const __half2* __restrict__ f1,
            const float* __restrict__ al0, const float* __restrict__ ar0,
            const float* __restrict__ al1, const float* __restrict__ ar1,
            float* __restrict__ el0, float* __restrict__ er0,
            float* __restrict__ el1, float* __restrict__ er1,
            unsigned* __restrict__ elmax) {
  __shared__ float sh[256];
  int i = blockIdx.x * 256 + threadIdx.x;  // over N*8
  bool valid = i < NN * NHEAD;
  int ii = valid ? i : 0;
  int h = ii & 7;
  const __half2* p0 = f0 + (size_t)ii * 8;
  const __half2* p1 = f1 + (size_t)ii * 8;
  float sl0 = 0.f, sr0 = 0.f, sl1 = 0.f, sr1 = 0.f;
#pragma unroll
  for (int d = 0; d < 8; ++d) {
    float2 a = __half22float2(p0[d]);
    float2 b = __half22float2(p1[d]);
    float l0a = al0[h * 16 + 2 * d], l0b = al0[h * 16 + 2 * d + 1];
    float r0a = ar0[h * 16 + 2 * d], r0b = ar0[h * 16 + 2 * d + 1];
    float l1a = al1[h * 16 + 2 * d], l1b = al1[h * 16 + 2 * d + 1];
    float r1a = ar1[h * 16 + 2 * d], r1b = ar1[h * 16 + 2 * d + 1];
    sl0 += a.x * l0a + a.y * l0b;  sr0 += a.x * r0a + a.y * r0b;
    sl1 += b.x * l1a + b.y * l1b;  sr1 += b.x * r1a + b.y * r1b;
  }
  if (valid) { el0[i] = sl0; er0[i] = sr0; el1[i] = sl1; er1[i] = sr1; }
  // block max of el0 per head -> atomicMax
  sh[threadIdx.x] = valid ? sl0 : -1e30f;
  __syncthreads();
#pragma unroll
  for (int off = 128; off >= 8; off >>= 1) {
    if (threadIdx.x < off) sh[threadIdx.x] = fmaxf(sh[threadIdx.x], sh[threadIdx.x + off]);
    __syncthreads();
  }
  if (threadIdx.x < 8) atomicMax(&elmax[threadIdx.x], fenc(sh[threadIdx.x]));
  __syncthreads();
  sh[threadIdx.x] = valid ? sl1 : -1e30f;
  __syncthreads();
#pragma unroll
  for (int off = 128; off >= 8; off >>= 1) {
    if (threadIdx.x < off) sh[threadIdx.x] = fmaxf(sh[threadIdx.x], sh[threadIdx.x + off]);
    __syncthreads();
  }
  if (threadIdx.x < 8) atomicMax(&elmax[8 + threadIdx.x], fenc(sh[threadIdx.x]));
}

// ---------------------------------------------------------------------------
// CSR build (both relations merged; rowptr[2][NN+1], csr[2][EE])
// ---------------------------------------------------------------------------
__global__ __launch_bounds__(256)
void hist_k(const int* __restrict__ dst, int* __restrict__ cnt) {
  int e = blockIdx.x * 256 + threadIdx.x;
  if (e < 2 * EE) {
    int idx = ((e >= EE) ? NN : 0) + dst[e];
    atomicAdd(&cnt[idx], 1);
  }
}

__global__ __launch_bounds__(256)
void scan_block_k(const int* __restrict__ in, int* __restrict__ out,
                  int* __restrict__ bsums, int n) {
  in += (size_t)blockIdx.y * n;
  out += (size_t)blockIdx.y * (n + 1);
  bsums += (size_t)blockIdx.y * 256;
  __shared__ int sh[256];
  int i = blockIdx.x * 256 + threadIdx.x;
  int v = (i < n) ? in[i] : 0;
  sh[threadIdx.x] = v;
  __syncthreads();
#pragma unroll
  for (int off = 1; off < 256; off <<= 1) {
    int t = (threadIdx.x >= off) ? sh[threadIdx.x - off] : 0;
    __syncthreads();
    sh[threadIdx.x] += t;
    __syncthreads();
  }
  if (i < n) out[i] = sh[threadIdx.x] - v;  // exclusive
  if (threadIdx.x == 255) bsums[blockIdx.x] = sh[255];
}

__global__ __launch_bounds__(256)
void scan_bsums_k(int* bsums, int nb) {
  bsums += (size_t)blockIdx.y * 256;
  __shared__ int sh[256];
  int v = (threadIdx.x < nb) ? bsums[threadIdx.x] : 0;
  sh[threadIdx.x] = v;
  __syncthreads();
#pragma unroll
  for (int off = 1; off < 256; off <<= 1) {
    int t = (threadIdx.x >= off) ? sh[threadIdx.x - off] : 0;
    __syncthreads();
    sh[threadIdx.x] += t;
    __syncthreads();
  }
  if (threadIdx.x < nb) bsums[threadIdx.x] = sh[threadIdx.x] - v;
}

__global__ __launch_bounds__(256)
void add_off_k(int* __restrict__ out, const int* __restrict__ bsums, int n) {
  out += (size_t)blockIdx.y * (n + 1);
  bsums += (size_t)blockIdx.y * 256;
  int i = blockIdx.x * 256 + threadIdx.x;
  if (i < n) out[i] += bsums[blockIdx.x];
  if (i == 0) out[n] = EE;
}

__global__ __launch_bounds__(256)
void fill_k(const int* __restrict__ src, const int* __restrict__ dst,
            const int* __restrict__ rowptr, int* __restrict__ cnt,
            int* __restrict__ csr) {
  int e = blockIdx.x * 256 + threadIdx.x;
  if (e >= 2 * EE) return;
  int r = (e >= EE) ? 1 : 0;
  int d = dst[e];
  const int* rp = rowptr + (size_t)r * (NN + 1);
  int p = rp[d] + atomicAdd(&cnt[r * NN + d], 1);
  csr[(size_t)r * EE + p] = src[e];
}

// ---------------------------------------------------------------------------
// GAT aggregate, both relations fused, bound-shift softmax (no online max):
// p = exp(e - B) with B = leaky(elmax[h] + er[n,h]) >= max e. Shift-invariant
// => exact softmax. One wave per node; lane owns features (2*lane, 2*lane+1);
// 4-edge batched loads keep ~1.2KB/wave in flight.
// ---------------------------------------------------------------------------
__device__ __forceinline__ float2 agg_rel(const __half2* __restrict__ feat,
                                          const float* __restrict__ el,
                                          float er_h, float bound,
                                          const int* __restrict__ csr,
                                          int beg, int end, int lane, int head) {
  float ls = 0.f, a0 = 0.f, a1 = 0.f;
  for (int t = beg; t < end; t += 4) {
    int s[4];
#pragma unroll
    for (int j = 0; j < 4; ++j) s[j] = csr[(t + j < end) ? (t + j) : (end - 1)];
    float ev[4];
#pragma unroll
    for (int j = 0; j < 4; ++j) ev[j] = el[(size_t)s[j] * 8 + head];
    __half2 f[4];
#pragma unroll
    for (int j = 0; j < 4; ++j) f[j] = feat[(size_t)s[j] * 64 + lane];
#pragma unroll
    for (int j = 0; j < 4; ++j) {
      float e = ev[j] + er_h;
      e = fmaxf(e, 0.2f * e);                  // leaky_relu 0.2
      float p = __expf(e - bound);             // e <= bound, no overflow
      p = (t + j < end) ? p : 0.f;             // padded tail
      float2 fv = __half22float2(f[j]);
      ls += p; a0 += p * fv.x; a1 += p * fv.y;
    }
  }
  float inv = (ls > 0.f) ? 1.f / ls : 0.f;     // isolated node -> rst = 0
  return make_float2(a0 * inv, a1 * inv);
}

__global__ __launch_bounds__(256)
void gat_agg_k(const __half2* __restrict__ f0, const __half2* __restrict__ f1,
               const float* __restrict__ el0, const float* __restrict__ er0,
               const float* __restrict__ el1, const float* __restrict__ er1,
               const int* __restrict__ rowptr, const int* __restrict__ csr,
               const float* __restrict__ b0, const float* __restrict__ b1,
               const unsigned* __restrict__ elmax,
               float* __restrict__ h1, _Float16* __restrict__ h1h) {
  int n = blockIdx.x * 4 + (threadIdx.x >> 6);
  if (n >= NN) return;
  int lane = threadIdx.x & 63;
  int head = lane >> 3;
  float er0h = er0[(size_t)n * 8 + head];
  float er1h = er1[(size_t)n * 8 + head];
  float bnd0 = fdec(elmax[head]) + er0h;       bnd0 = fmaxf(bnd0, 0.2f * bnd0);
  float bnd1 = fdec(elmax[8 + head]) + er1h;   bnd1 = fmaxf(bnd1, 0.2f * bnd1);
  float2 r0 = agg_rel(f0, el0, er0h, bnd0, csr, rowptr[n], rowptr[n + 1], lane, head);
  const int* rp1 = rowptr + (NN + 1);
  float2 r1 = agg_rel(f1, el1, er1h, bnd1, csr + EE, rp1[n], rp1[n + 1], lane, head);
  float t0 = r0.x + r1.x + b0[lane * 2] + b1[lane * 2];
  float t1 = r0.y + r1.y + b0[lane * 2 + 1] + b1[lane * 2 + 1];
  t0 = (t0 > 0.f) ? t0 : 0.01f * t0;           // leaky_relu 0.01
  t1 = (t1 > 0.f) ? t1 : 0.01f * t1;
  float2* h2p = (float2*)h1 + (size_t)n * 64 + lane;
  float2 h = *h2p;
  h.x += t0; h.y += t1;
  *h2p = h;
  __half2* hh = (__half2*)h1h + (size_t)n * 64 + lane;
  *hh = __floats2half2_rn(h.x, h.y);
}

// ---------------------------------------------------------------------------
extern "C" void kernel_launch(void* const* d_in, const int* in_sizes, int n_in,
                              void* d_out, int out_size, void* d_ws,
                              size_t ws_size, hipStream_t stream) {
  const float* inputs = (const float*)d_in[0];
  const int* src = (const int*)d_in[1];
  const int* dst = (const int*)d_in[2];
  const float* ew1 = (const float*)d_in[3];
  const float* eg = (const float*)d_in[4];
  const float* eb = (const float*)d_in[5];
  const float* ew2 = (const float*)d_in[6];
  const float* gfc = (const float*)d_in[7];
  const float* gal = (const float*)d_in[8];
  const float* gar = (const float*)d_in[9];
  const float* gb = (const float*)d_in[10];
  const float* dw1 = (const float*)d_in[11];
  const float* dg = (const float*)d_in[12];
  const float* db = (const float*)d_in[13];
  const float* dw2 = (const float*)d_in[14];
  float* out = (float*)d_out;

  // ---- workspace layout (~78 MB) ----
  char* p = (char*)d_ws;
  float* h1 = (float*)p;            p += (size_t)NN * 128 * 4;   // 25.6MB
  float* ybuf = (float*)p;                                        // MLP phases
  _Float16* feat0h = (_Float16*)p;                                // GAT phase
  _Float16* feat1h = feat0h + (size_t)NN * 128;
  p += (size_t)NN * 128 * 4;
  _Float16* h1h = (_Float16*)p;     p += (size_t)NN * 128 * 2;   // 12.8MB
  float* el0 = (float*)p;           p += (size_t)NN * NHEAD * 4;
  float* er0 = (float*)p;           p += (size_t)NN * NHEAD * 4;
  float* el1 = (float*)p;           p += (size_t)NN * NHEAD * 4;
  float* er1 = (float*)p;           p += (size_t)NN * NHEAD * 4;
  float* stats = (float*)p;         p += 1024 * 4;  // stats_e | stats_d
  float* stats_e = stats;
  float* stats_d = stats + 512;
  unsigned* elmax = (unsigned*)p;   p += 16 * 4;
  _Float16* wt = (_Float16*)p;      p += (size_t)(8192 + 16384 * 10 + 4096) * 2;
  _Float16* ew1t = wt;                       // [128][64]
  _Float16* ew2t = wt + 8192;                // [128][128]
  _Float16* gfct = ew2t + 16384;             // 8 x [128][128]
  _Float16* dw1t = gfct + 8 * 16384;         // [128][128]
  _Float16* dw2t = dw1t + 16384;             // [32][128]
  int* rowptr = (int*)p;            p += (size_t)2 * (NN + 1) * 4;
  int* csr = (int*)p;               p += (size_t)2 * EE * 4;
  int* cnt = (int*)p;               p += (size_t)2 * NN * 4;
  // bsums: 2x256 ints
  int* bsums = (int*)p;

  const int SCB = (NN + 255) / 256;        // 196
  const int EGB2 = (2 * EE + 255) / 256;   // 6250
  const int GB = (NN + 127) / 128;         // 391
  const int ELB = (NN * NHEAD + 255) / 256;

  // ---- CSR build (both relations in one pass chain) ----
  hipMemsetAsync(cnt, 0, 2 * NN * sizeof(int), stream);
  hist_k<<<EGB2, 256, 0, stream>>>(dst, cnt);
  scan_block_k<<<dim3(SCB, 2), 256, 0, stream>>>(cnt, rowptr, bsums, NN);
  scan_bsums_k<<<dim3(1, 2), 256, 0, stream>>>(bsums, SCB);
  add_off_k<<<dim3(SCB, 2), 256, 0, stream>>>(rowptr, bsums, NN);
  hipMemsetAsync(cnt, 0, 2 * NN * sizeof(int), stream);
  fill_k<<<EGB2, 256, 0, stream>>>(src, dst, rowptr, cnt, csr);

  // ---- weight transpose/convert + zero BN stats ----
  {
    TJobs jobs;
    jobs.j[0] = {ew1, ew1t, 64, 128};
    jobs.j[1] = {ew2, ew2t, 128, 128};
    for (int i = 0; i < 8; ++i)
      jobs.j[2 + i] = {gfc + (size_t)i * 16384, gfct + (size_t)i * 16384, 128, 128};
    jobs.j[10] = {dw1, dw1t, 128, 128};
    jobs.j[11] = {dw2, dw2t, 128, 32};
    transpose_k<<<12, 256, 0, stream>>>(jobs, stats);
  }

  // ---- embed MLP: y = x@w1 (+stats); h = relu(bn(y)); h1 = h@w2 + h ----
  mfma_gemm_k<64, 128, float, false, false, true, false, true, false>
      <<<GB, 256, 0, stream>>>(inputs, ew1t, nullptr, stats_e, nullptr,
                               nullptr, ybuf, nullptr, NN);
  bn_final_k<<<1, 128, 0, stream>>>(stats_e, eg, eb);
  mfma_gemm_k<128, 128, float, true, true, false, true, true, false>
      <<<GB, 256, 0, stream>>>(ybuf, ew2t, stats_e, nullptr, ybuf,
                               h1h, h1, nullptr, NN);

  // ---- 4 GAT layers ----
  for (int l = 0; l < 4; ++l) {
    _Float16* wt0 = gfct + (size_t)(l * 2 + 0) * 16384;
    _Float16* wt1 = gfct + (size_t)(l * 2 + 1) * 16384;
    mfma_gemm_k<128, 128, _Float16, false, false, false, true, false, true>
        <<<GB, 256, 0, stream>>>(h1h, wt0, nullptr, nullptr, nullptr,
                                 feat0h, nullptr, elmax, NN);
    mfma_gemm_k<128, 128, _Float16, false, false, false, true, false, true>
        <<<GB, 256, 0, stream>>>(h1h, wt1, nullptr, nullptr, nullptr,
                                 feat1h, nullptr, elmax, NN);
    eler_k<<<ELB, 256, 0, stream>>>(
        (const __half2*)feat0h, (const __half2*)feat1h,
        gal + (size_t)(l * 2 + 0) * 128, gar + (size_t)(l * 2 + 0) * 128,
        gal + (size_t)(l * 2 + 1) * 128, gar + (size_t)(l * 2 + 1) * 128,
        el0, er0, el1, er1, elmax);
    gat_agg_k<<<(NN + 3) / 4, 256, 0, stream>>>(
        (const __half2*)feat0h, (const __half2*)feat1h, el0, er0, el1, er1,
        rowptr, csr, gb + (size_t)(l * 2 + 0) * 128,
        gb + (size_t)(l * 2 + 1) * 128, elmax, h1, h1h);
  }

  // ---- decision MLP: y = h1@dw1 (+stats); out = relu(bn(y)) @ dw2 ----
  mfma_gemm_k<128, 128, _Float16, false, false, true, false, true, false>
      <<<GB, 256, 0, stream>>>(h1h, dw1t, nullptr, stats_d, nullptr,
                               nullptr, ybuf, nullptr, NN);
  bn_final_k<<<1, 128, 0, stream>>>(stats_d, dg, db);
  mfma_gemm_k<128, 32, float, true, false, false, false, true, false>
      <<<GB, 256, 0, stream>>>(ybuf, dw2t, stats_d, nullptr, nullptr,
                               nullptr, out, nullptr, NN);
}

// Round 6
// 966.432 us; speedup vs baseline: 1.0759x; 1.0759x over previous
//
#include <hip/hip_runtime.h>
#include <hip/hip_fp16.h>
#include <math.h>

#define NN 50000
#define EE 800000
#define NHEAD 8
#define BN_EPS 1e-5f

typedef _Float16 half8_t __attribute__((ext_vector_type(8)));
typedef float float4_t __attribute__((ext_vector_type(4)));

// monotone float<->uint encoding for atomicMax on signed floats
__device__ __forceinline__ unsigned fenc(float f) {
  unsigned u = __float_as_uint(f);
  return (u & 0x80000000u) ? ~u : (u | 0x80000000u);
}
__device__ __forceinline__ float fdec(unsigned k) {
  return (k & 0x80000000u) ? __uint_as_float(k & 0x7fffffffu)
                           : __uint_as_float(~k);
}

// bn scale/shift from raw sums (stats[c]=sum, stats[128+c]=sumsq)
__device__ __forceinline__ void bn_coef(const float* __restrict__ stats,
                                        const float* __restrict__ gamma,
                                        const float* __restrict__ beta,
                                        int c, float& sc, float& sh) {
  float mean = stats[c] * (1.f / NN);
  float var = fmaxf(stats[128 + c] * (1.f / NN) - mean * mean, 0.f);
  sc = gamma[c] * rsqrtf(var + BN_EPS);
  sh = beta[c] - mean * sc;
}

// ---------------------------------------------------------------------------
// Unified MFMA GEMM: C[M,NC] = A[M,KDIM] @ B, Bt = B^T [NC][KDIM] fp16.
// ABN: A is fp32, relu(bn(A)) applied on load (coef from raw stats+gamma/beta)
// STATS: fused BatchNorm column sum/sumsq accumulation (atomicAdd).
// RESIDBN: adds relu(bn(residf[row,col])) to output (embed residual).
// CLR: block 0 zeroes 16 uints (elmax) for the following eler pass.
// ---------------------------------------------------------------------------
template <int KDIM, int NC, typename AT, bool ABN, bool RESIDBN, bool STATS,
          bool F16OUT, bool F32OUT, bool CLR>
__global__ __launch_bounds__(256)
void mfma_gemm_k(const AT* __restrict__ A, const _Float16* __restrict__ Bt,
                 const float* __restrict__ bn, const float* __restrict__ gamma,
                 const float* __restrict__ beta, float* __restrict__ statsOut,
                 const float* __restrict__ residf, _Float16* __restrict__ Ch,
                 float* __restrict__ Cf, unsigned* __restrict__ clrp, int M) {
  constexpr int NT = NC / 16;
  const int lane = threadIdx.x & 63, wave = threadIdx.x >> 6;
  const int q = lane >> 4, l16 = lane & 15;
  const int row0 = blockIdx.x * 128 + wave * 32;
  if constexpr (CLR) {
    if (blockIdx.x == 0 && threadIdx.x < 16) clrp[threadIdx.x] = 0u;
  }
  float4_t acc[2][NT];
#pragma unroll
  for (int i = 0; i < 2; ++i)
#pragma unroll
    for (int j = 0; j < NT; ++j) acc[i][j] = (float4_t){0.f, 0.f, 0.f, 0.f};

#pragma unroll
  for (int kk = 0; kk < KDIM / 32; ++kk) {
    float scv[8], shv[8];
    if constexpr (ABN) {
      int kb = kk * 32 + q * 8;
#pragma unroll
      for (int x = 0; x < 8; ++x) bn_coef(bn, gamma, beta, kb + x, scv[x], shv[x]);
    }
    half8_t a[2];
#pragma unroll
    for (int i = 0; i < 2; ++i) {
      int r = row0 + i * 16 + l16;
      r = (r < M) ? r : (M - 1);
      if constexpr (__is_same(AT, _Float16)) {
        a[i] = *(const half8_t*)(A + (size_t)r * KDIM + kk * 32 + q * 8);
      } else {
        const float* ap = (const float*)A + (size_t)r * KDIM + kk * 32 + q * 8;
        float4 v0 = *(const float4*)ap, v1 = *(const float4*)(ap + 4);
        float t[8] = {v0.x, v0.y, v0.z, v0.w, v1.x, v1.y, v1.z, v1.w};
        if constexpr (ABN) {
#pragma unroll
          for (int x = 0; x < 8; ++x) t[x] = fmaxf(t[x] * scv[x] + shv[x], 0.f);
        }
        half8_t hv;
#pragma unroll
        for (int x = 0; x < 8; ++x) hv[x] = (_Float16)t[x];
        a[i] = hv;
      }
    }
#pragma unroll
    for (int j = 0; j < NT; ++j) {
      half8_t b = *(const half8_t*)(Bt + (size_t)(j * 16 + l16) * KDIM + kk * 32 + q * 8);
      acc[0][j] = __builtin_amdgcn_mfma_f32_16x16x32_f16(a[0], b, acc[0][j], 0, 0, 0);
      acc[1][j] = __builtin_amdgcn_mfma_f32_16x16x32_f16(a[1], b, acc[1][j], 0, 0, 0);
    }
  }

  // store epilogue (C/D: col=lane&15, row=(lane>>4)*4+reg)
  float rsc[NT], rsh[NT];
  if constexpr (RESIDBN) {
#pragma unroll
    for (int j = 0; j < NT; ++j) bn_coef(bn, gamma, beta, j * 16 + l16, rsc[j], rsh[j]);
  }
#pragma unroll
  for (int i = 0; i < 2; ++i)
#pragma unroll
    for (int j = 0; j < NT; ++j)
#pragma unroll
      for (int r = 0; r < 4; ++r) {
        int row = row0 + i * 16 + q * 4 + r;
        if (row >= M) continue;
        int col = j * 16 + l16;
        float v = acc[i][j][r];
        if constexpr (RESIDBN) {
          float rv = residf[(size_t)row * NC + col];
          v += fmaxf(rv * rsc[j] + rsh[j], 0.f);
        }
        if constexpr (F32OUT) Cf[(size_t)row * NC + col] = v;
        if constexpr (F16OUT) Ch[(size_t)row * NC + col] = (_Float16)v;
      }

  if constexpr (STATS) {
    float sc_[NT], sq_[NT];
#pragma unroll
    for (int j = 0; j < NT; ++j) {
      float s = 0.f, qq = 0.f;
#pragma unroll
      for (int i = 0; i < 2; ++i)
#pragma unroll
        for (int r = 0; r < 4; ++r) {
          int row = row0 + i * 16 + q * 4 + r;
          float x = (row < M) ? acc[i][j][r] : 0.f;
          s += x; qq += x * x;
        }
      sc_[j] = s; sq_[j] = qq;
    }
#pragma unroll
    for (int j = 0; j < NT; ++j) {
      sc_[j] += __shfl_xor(sc_[j], 16, 64);
      sq_[j] += __shfl_xor(sq_[j], 16, 64);
      sc_[j] += __shfl_xor(sc_[j], 32, 64);
      sq_[j] += __shfl_xor(sq_[j], 32, 64);
    }
    if (lane < 16) {
#pragma unroll
      for (int j = 0; j < NT; ++j) {
        atomicAdd(&statsOut[j * 16 + l16], sc_[j]);
        atomicAdd(&statsOut[128 + j * 16 + l16], sq_[j]);
      }
    }
  }
}

// ---------------------------------------------------------------------------
// weight transpose + fp32->fp16 (12 matrices) + zero both BN stats buffers
// ---------------------------------------------------------------------------
struct TJob { const float* src; _Float16* dst; int k, n; };
struct TJobs { TJob j[12]; };

__global__ __launch_bounds__(256)
void transpose_k(TJobs jobs, float* __restrict__ statsz) {
  if (blockIdx.x == 0) {
    for (int i = threadIdx.x; i < 1024; i += 256) statsz[i] = 0.f;
  }
  TJob job = jobs.j[blockIdx.x];
  int total = job.k * job.n;
  for (int i = threadIdx.x; i < total; i += 256) {
    int kk = i / job.n, nn = i % job.n;
    job.dst[(size_t)nn * job.k + kk] = (_Float16)job.src[i];
  }
}

// ---------------------------------------------------------------------------
// attention logits for BOTH relations + per-head global el max (encoded)
// ---------------------------------------------------------------------------
__global__ __launch_bounds__(256)
void eler_k(const __half2* __restrict__ f0, const __half2* __restrict__ f1,
            const float* __restrict__ al0, const float* __restrict__ ar0,
            const float* __restrict__ al1, const float* __restrict__ ar1,
            float* __restrict__ el0, float* __restrict__ er0,
            float* __restrict__ el1, float* __restrict__ er1,
            unsigned* __restrict__ elmax) {
  __shared__ float sh[256];
  int i = blockIdx.x * 256 + threadIdx.x;  // over N*8
  bool valid = i < NN * NHEAD;
  int ii = valid ? i : 0;
  int h = ii & 7;
  const __half2* p0 = f0 + (size_t)ii * 8;
  const __half2* p1 = f1 + (size_t)ii * 8;
  float sl0 = 0.f, sr0 = 0.f, sl1 = 0.f, sr1 = 0.f;
#pragma unroll
  for (int d = 0; d < 8; ++d) {
    float2 a = __half22float2(p0[d]);
    float2 b = __half22float2(p1[d]);
    sl0 += a.x * al0[h * 16 + 2 * d] + a.y * al0[h * 16 + 2 * d + 1];
    sr0 += a.x * ar0[h * 16 + 2 * d] + a.y * ar0[h * 16 + 2 * d + 1];
    sl1 += b.x * al1[h * 16 + 2 * d] + b.y * al1[h * 16 + 2 * d + 1];
    sr1 += b.x * ar1[h * 16 + 2 * d] + b.y * ar1[h * 16 + 2 * d + 1];
  }
  if (valid) { el0[i] = sl0; er0[i] = sr0; el1[i] = sl1; er1[i] = sr1; }
  sh[threadIdx.x] = valid ? sl0 : -1e30f;
  __syncthreads();
#pragma unroll
  for (int off = 128; off >= 8; off >>= 1) {
    if (threadIdx.x < off) sh[threadIdx.x] = fmaxf(sh[threadIdx.x], sh[threadIdx.x + off]);
    __syncthreads();
  }
  if (threadIdx.x < 8) atomicMax(&elmax[threadIdx.x], fenc(sh[threadIdx.x]));
  __syncthreads();
  sh[threadIdx.x] = valid ? sl1 : -1e30f;
  __syncthreads();
#pragma unroll
  for (int off = 128; off >= 8; off >>= 1) {
    if (threadIdx.x < off) sh[threadIdx.x] = fmaxf(sh[threadIdx.x], sh[threadIdx.x + off]);
    __syncthreads();
  }
  if (threadIdx.x < 8) atomicMax(&elmax[8 + threadIdx.x], fenc(sh[threadIdx.x]));
}

// ---------------------------------------------------------------------------
// CSR build: hist records per-edge rank (no atomics in fill); csr is uint16
// (src < 50000 < 2^16) to halve scatter-write amplification.
// ---------------------------------------------------------------------------
__global__ __launch_bounds__(256)
void hist_rank_k(const int* __restrict__ dst, int* __restrict__ cnt,
                 unsigned short* __restrict__ rank) {
  int e = blockIdx.x * 256 + threadIdx.x;
  if (e < 2 * EE) {
    int idx = ((e >= EE) ? NN : 0) + dst[e];
    rank[e] = (unsigned short)atomicAdd(&cnt[idx], 1);
  }
}

__global__ __launch_bounds__(256)
void scan_block_k(const int* __restrict__ in, int* __restrict__ out,
                  int* __restrict__ bsums, int n) {
  in += (size_t)blockIdx.y * n;
  out += (size_t)blockIdx.y * (n + 1);
  bsums += (size_t)blockIdx.y * 256;
  __shared__ int sh[256];
  int i = blockIdx.x * 256 + threadIdx.x;
  int v = (i < n) ? in[i] : 0;
  sh[threadIdx.x] = v;
  __syncthreads();
#pragma unroll
  for (int off = 1; off < 256; off <<= 1) {
    int t = (threadIdx.x >= off) ? sh[threadIdx.x - off] : 0;
    __syncthreads();
    sh[threadIdx.x] += t;
    __syncthreads();
  }
  if (i < n) out[i] = sh[threadIdx.x] - v;  // exclusive
  if (threadIdx.x == 255) bsums[blockIdx.x] = sh[255];
}

// add exclusive-prefix of bsums[0..bx) (computed in-block) to out
__global__ __launch_bounds__(256)
void add_off_k(int* __restrict__ out, const int* __restrict__ bsums, int n) {
  out += (size_t)blockIdx.y * (n + 1);
  bsums += (size_t)blockIdx.y * 256;
  __shared__ int sh[256];
  int b = (threadIdx.x < blockIdx.x) ? bsums[threadIdx.x] : 0;
  sh[threadIdx.x] = b;
  __syncthreads();
#pragma unroll
  for (int off = 128; off >= 1; off >>= 1) {
    if (threadIdx.x < off) sh[threadIdx.x] += sh[threadIdx.x + off];
    __syncthreads();
  }
  int pre = sh[0];
  int i = blockIdx.x * 256 + threadIdx.x;
  if (i < n) out[i] += pre;
  if (i == 0) out[n] = EE;
}

__global__ __launch_bounds__(256)
void fill_k(const int* __restrict__ src, const int* __restrict__ dst,
            const int* __restrict__ rowptr, const unsigned short* __restrict__ rank,
            unsigned short* __restrict__ csr) {
  int e = blockIdx.x * 256 + threadIdx.x;
  if (e >= 2 * EE) return;
  int r = (e >= EE) ? 1 : 0;
  int d = dst[e];
  const int* rp = rowptr + (size_t)r * (NN + 1);
  int p = rp[d] + (int)rank[e];
  csr[(size_t)r * EE + p] = (unsigned short)src[e];
}

// ---------------------------------------------------------------------------
// GAT aggregate, both relations fused, bound-shift softmax (exact, no online
// max): p = exp(e - B), B = leaky(elmax[h] + er[n,h]) >= max e. One wave per
// node; lane owns features (2*lane, 2*lane+1); 4-edge batched loads.
// ---------------------------------------------------------------------------
__device__ __forceinline__ float2 agg_rel(const __half2* __restrict__ feat,
                                          const float* __restrict__ el,
                                          float er_h, float bound,
                                          const unsigned short* __restrict__ csr,
                                          int beg, int end, int lane, int head) {
  float ls = 0.f, a0 = 0.f, a1 = 0.f;
  for (int t = beg; t < end; t += 4) {
    int s[4];
#pragma unroll
    for (int j = 0; j < 4; ++j) s[j] = (int)csr[(t + j < end) ? (t + j) : (end - 1)];
    float ev[4];
#pragma unroll
    for (int j = 0; j < 4; ++j) ev[j] = el[(size_t)s[j] * 8 + head];
    __half2 f[4];
#pragma unroll
    for (int j = 0; j < 4; ++j) f[j] = feat[(size_t)s[j] * 64 + lane];
#pragma unroll
    for (int j = 0; j < 4; ++j) {
      float e = ev[j] + er_h;
      e = fmaxf(e, 0.2f * e);                  // leaky_relu 0.2
      float p = __expf(e - bound);             // e <= bound, no overflow
      p = (t + j < end) ? p : 0.f;             // padded tail
      float2 fv = __half22float2(f[j]);
      ls += p; a0 += p * fv.x; a1 += p * fv.y;
    }
  }
  float inv = (ls > 0.f) ? 1.f / ls : 0.f;     // isolated node -> rst = 0
  return make_float2(a0 * inv, a1 * inv);
}

__global__ __launch_bounds__(256)
void gat_agg_k(const __half2* __restrict__ f0, const __half2* __restrict__ f1,
               const float* __restrict__ el0, const float* __restrict__ er0,
               const float* __restrict__ el1, const float* __restrict__ er1,
               const int* __restrict__ rowptr, const unsigned short* __restrict__ csr,
               const float* __restrict__ b0, const float* __restrict__ b1,
               const unsigned* __restrict__ elmax,
               float* __restrict__ h1, _Float16* __restrict__ h1h) {
  int n = blockIdx.x * 4 + (threadIdx.x >> 6);
  if (n >= NN) return;
  int lane = threadIdx.x & 63;
  int head = lane >> 3;
  float er0h = er0[(size_t)n * 8 + head];
  float er1h = er1[(size_t)n * 8 + head];
  float bnd0 = fdec(elmax[head]) + er0h;       bnd0 = fmaxf(bnd0, 0.2f * bnd0);
  float bnd1 = fdec(elmax[8 + head]) + er1h;   bnd1 = fmaxf(bnd1, 0.2f * bnd1);
  float2 r0 = agg_rel(f0, el0, er0h, bnd0, csr, rowptr[n], rowptr[n + 1], lane, head);
  const int* rp1 = rowptr + (NN + 1);
  float2 r1 = agg_rel(f1, el1, er1h, bnd1, csr + EE, rp1[n], rp1[n + 1], lane, head);
  float t0 = r0.x + r1.x + b0[lane * 2] + b1[lane * 2];
  float t1 = r0.y + r1.y + b0[lane * 2 + 1] + b1[lane * 2 + 1];
  t0 = (t0 > 0.f) ? t0 : 0.01f * t0;           // leaky_relu 0.01
  t1 = (t1 > 0.f) ? t1 : 0.01f * t1;
  float2* h2p = (float2*)h1 + (size_t)n * 64 + lane;
  float2 h = *h2p;
  h.x += t0; h.y += t1;
  *h2p = h;
  __half2* hh = (__half2*)h1h + (size_t)n * 64 + lane;
  *hh = __floats2half2_rn(h.x, h.y);
}

// ---------------------------------------------------------------------------
extern "C" void kernel_launch(void* const* d_in, const int* in_sizes, int n_in,
                              void* d_out, int out_size, void* d_ws,
                              size_t ws_size, hipStream_t stream) {
  const float* inputs = (const float*)d_in[0];
  const int* src = (const int*)d_in[1];
  const int* dst = (const int*)d_in[2];
  const float* ew1 = (const float*)d_in[3];
  const float* eg = (const float*)d_in[4];
  const float* eb = (const float*)d_in[5];
  const float* ew2 = (const float*)d_in[6];
  const float* gfc = (const float*)d_in[7];
  const float* gal = (const float*)d_in[8];
  const float* gar = (const float*)d_in[9];
  const float* gb = (const float*)d_in[10];
  const float* dw1 = (const float*)d_in[11];
  const float* dg = (const float*)d_in[12];
  const float* db = (const float*)d_in[13];
  const float* dw2 = (const float*)d_in[14];
  float* out = (float*)d_out;

  // ---- workspace layout ----
  char* p = (char*)d_ws;
  float* h1 = (float*)p;            p += (size_t)NN * 128 * 4;   // 25.6MB
  float* ybuf = (float*)p;                                        // MLP phases
  _Float16* feat0h = (_Float16*)p;                                // GAT phase
  _Float16* feat1h = feat0h + (size_t)NN * 128;
  p += (size_t)NN * 128 * 4;
  _Float16* h1h = (_Float16*)p;     p += (size_t)NN * 128 * 2;   // 12.8MB
  float* el0 = (float*)p;           p += (size_t)NN * NHEAD * 4;
  float* er0 = (float*)p;           p += (size_t)NN * NHEAD * 4;
  float* el1 = (float*)p;           p += (size_t)NN * NHEAD * 4;
  float* er1 = (float*)p;           p += (size_t)NN * NHEAD * 4;
  float* stats = (float*)p;         p += 1024 * 4;  // stats_e | stats_d
  float* stats_e = stats;
  float* stats_d = stats + 512;
  unsigned* elmax = (unsigned*)p;   p += 16 * 4;
  _Float16* wt = (_Float16*)p;      p += (size_t)(8192 + 16384 * 10 + 4096) * 2;
  _Float16* ew1t = wt;                       // [128][64]
  _Float16* ew2t = wt + 8192;                // [128][128]
  _Float16* gfct = ew2t + 16384;             // 8 x [128][128]
  _Float16* dw1t = gfct + 8 * 16384;         // [128][128]
  _Float16* dw2t = dw1t + 16384;             // [32][128]
  int* rowptr = (int*)p;            p += (size_t)2 * (NN + 1) * 4;
  unsigned short* csr = (unsigned short*)p;   p += (size_t)2 * EE * 2;
  unsigned short* rank = (unsigned short*)p;  p += (size_t)2 * EE * 2;
  int* cnt = (int*)p;               p += (size_t)2 * NN * 4;
  int* bsums = (int*)p;             // 2x256 ints

  const int SCB = (NN + 255) / 256;        // 196
  const int EGB2 = (2 * EE + 255) / 256;   // 6250
  const int GB = (NN + 127) / 128;         // 391
  const int ELB = (NN * NHEAD + 255) / 256;

  // ---- CSR build (rank recorded in hist; atomic-free uint16 fill) ----
  hipMemsetAsync(cnt, 0, 2 * NN * sizeof(int), stream);
  hist_rank_k<<<EGB2, 256, 0, stream>>>(dst, cnt, rank);
  scan_block_k<<<dim3(SCB, 2), 256, 0, stream>>>(cnt, rowptr, bsums, NN);
  add_off_k<<<dim3(SCB, 2), 256, 0, stream>>>(rowptr, bsums, NN);
  fill_k<<<EGB2, 256, 0, stream>>>(src, dst, rowptr, rank, csr);

  // ---- weight transpose/convert + zero BN stats ----
  {
    TJobs jobs;
    jobs.j[0] = {ew1, ew1t, 64, 128};
    jobs.j[1] = {ew2, ew2t, 128, 128};
    for (int i = 0; i < 8; ++i)
      jobs.j[2 + i] = {gfc + (size_t)i * 16384, gfct + (size_t)i * 16384, 128, 128};
    jobs.j[10] = {dw1, dw1t, 128, 128};
    jobs.j[11] = {dw2, dw2t, 128, 32};
    transpose_k<<<12, 256, 0, stream>>>(jobs, stats);
  }

  // ---- embed MLP: y = x@w1 (+stats); h1 = relu(bn(y))@w2 + relu(bn(y)) ----
  mfma_gemm_k<64, 128, float, false, false, true, false, true, false>
      <<<GB, 256, 0, stream>>>(inputs, ew1t, nullptr, nullptr, nullptr,
                               stats_e, nullptr, nullptr, ybuf, nullptr, NN);
  mfma_gemm_k<128, 128, float, true, true, false, true, true, false>
      <<<GB, 256, 0, stream>>>(ybuf, ew2t, stats_e, eg, eb, nullptr, ybuf,
                               h1h, h1, nullptr, NN);

  // ---- 4 GAT layers ----
  for (int l = 0; l < 4; ++l) {
    _Float16* wt0 = gfct + (size_t)(l * 2 + 0) * 16384;
    _Float16* wt1 = gfct + (size_t)(l * 2 + 1) * 16384;
    mfma_gemm_k<128, 128, _Float16, false, false, false, true, false, true>
        <<<GB, 256, 0, stream>>>(h1h, wt0, nullptr, nullptr, nullptr, nullptr,
                                 nullptr, feat0h, nullptr, elmax, NN);
    mfma_gemm_k<128, 128, _Float16, false, false, false, true, false, true>
        <<<GB, 256, 0, stream>>>(h1h, wt1, nullptr, nullptr, nullptr, nullptr,
                                 nullptr, feat1h, nullptr, elmax, NN);
    eler_k<<<ELB, 256, 0, stream>>>(
        (const __half2*)feat0h, (const __half2*)feat1h,
        gal + (size_t)(l * 2 + 0) * 128, gar + (size_t)(l * 2 + 0) * 128,
        gal + (size_t)(l * 2 + 1) * 128, gar + (size_t)(l * 2 + 1) * 128,
        el0, er0, el1, er1, elmax);
    gat_agg_k<<<(NN + 3) / 4, 256, 0, stream>>>(
        (const __half2*)feat0h, (const __half2*)feat1h, el0, er0, el1, er1,
        rowptr, csr, gb + (size_t)(l * 2 + 0) * 128,
        gb + (size_t)(l * 2 + 1) * 128, elmax, h1, h1h);
  }

  // ---- decision MLP: y = h1@dw1 (+stats); out = relu(bn(y)) @ dw2 ----
  mfma_gemm_k<128, 128, _Float16, false, false, true, false, true, false>
      <<<GB, 256, 0, stream>>>(h1h, dw1t, nullptr, nullptr, nullptr, stats_d,
                               nullptr, nullptr, ybuf, nullptr, NN);
  mfma_gemm_k<128, 32, float, true, false, false, false, true, false>
      <<<GB, 256, 0, stream>>>(ybuf, dw2t, stats_d, dg, db, nullptr, nullptr,
                               nullptr, out, nullptr, NN);
}